// Round 2
// baseline (465.343 us; speedup 1.0000x reference)
//
#include <hip/hip_runtime.h>
#include <hip/hip_bf16.h>
#include <math.h>

typedef __bf16 bf16;
typedef __attribute__((ext_vector_type(8))) __bf16 bf16x8;
typedef __attribute__((ext_vector_type(4))) __bf16 bf16x4;
typedef __attribute__((ext_vector_type(4))) float f32x4;

#define B_  4
#define S_  2048
#define D_  1024
#define H_  16
#define DH_ 64
#define M_  (B_ * S_)   // 8192

static __device__ __forceinline__ f32x4 mfma16(bf16x8 a, bf16x8 b, f32x4 c) {
  return __builtin_amdgcn_mfma_f32_16x16x32_bf16(a, b, c, 0, 0, 0);
}

static __device__ __forceinline__ void gld_lds16(const bf16* g, bf16* l) {
  __builtin_amdgcn_global_load_lds(
      (const __attribute__((address_space(1))) void*)g,
      (__attribute__((address_space(3))) void*)l, 16, 0, 0);
}

// ---------------- f32 -> bf16 cast (4 elems/thread) ----------------
__global__ __launch_bounds__(256)
void cast_kernel(const float* __restrict__ in, bf16* __restrict__ out) {
  size_t i = ((size_t)blockIdx.x * 256 + threadIdx.x) * 4;
  float4 v = *(const float4*)(in + i);
  bf16x4 o = {(bf16)v.x, (bf16)v.y, (bf16)v.z, (bf16)v.w};
  *(bf16x4*)(out + i) = o;
}

// ---------------- transpose+cast: out[n][k] = bf16(in[k][n]), 1024x1024 ----------------
__global__ __launch_bounds__(256)
void transpose_cast_kernel(const float* __restrict__ in, bf16* __restrict__ out) {
  __shared__ float tile[32][33];
  int n0 = blockIdx.x * 32, k0 = blockIdx.y * 32;
  int tx = threadIdx.x, ty = threadIdx.y;
#pragma unroll
  for (int j = 0; j < 32; j += 8)
    tile[ty + j][tx] = in[(size_t)(k0 + ty + j) * D_ + n0 + tx];
  __syncthreads();
#pragma unroll
  for (int j = 0; j < 32; j += 8)
    out[(size_t)(n0 + ty + j) * D_ + k0 + tx] = (bf16)tile[tx][ty + j];
}

// ---------------- bias table: tab[h*4096 + (s-t+2047)] ----------------
__global__ __launch_bounds__(256)
void bias_table_kernel(const float* __restrict__ rel_bias, float* __restrict__ tab) {
  int i = blockIdx.x * 256 + threadIdx.x;   // 16*4096 entries
  int h = i >> 12, dp = i & 4095;
  int rel = dp - 2047;                       // rel = s - t
  int bucket = (rel > 0) ? 16 : 0;
  int rp = rel < 0 ? -rel : rel;
  if (rp < 8) {
    bucket += rp;
  } else {
    // ln(rp/8)/ln(16)*8 == 2*log2(rp/8); exact at rp = 16,32,64,128 boundaries
    int large = 8 + (int)(2.0f * __log2f((float)rp * 0.125f));
    bucket += (large < 15 ? large : 15);
  }
  tab[i] = rel_bias[bucket * H_ + h];
}

// ---------------- GEMM: C[MxN] = A[MxK] * Bt[NxK]^T  (m97 structure) ----------------
// EPI 0: f32 row-major MxN.  EPI 1: bf16 [B,H,S,dh].  EPI 2: bf16 [B,H,dh,S] (V transposed)
template<int EPI>
__global__ __launch_bounds__(256)
void gemm_bt_kernel(const bf16* __restrict__ A, const bf16* __restrict__ Bt,
                    void* __restrict__ Cout) {
  const int K = D_, N = D_;
  __shared__ bf16 As[128][32];
  __shared__ bf16 Bs[128][32];
  const int tid = threadIdx.x;
  const int brow = blockIdx.y * 128, bcol = blockIdx.x * 128;
  const int wave = tid >> 6, lane = tid & 63;
  const int wr = (wave >> 1) * 64, wc = (wave & 1) * 64;
  const int lrow = lane & 15, lgrp = lane >> 4;

  f32x4 acc[4][4] = {};

  // thread tid stages tile rows (tid>>2) and 64+(tid>>2), col chunk (tid&3)*8
  const bf16* ag = A + (size_t)(brow + (tid >> 2)) * K + (tid & 3) * 8;
  const bf16* bg = Bt + (size_t)(bcol + (tid >> 2)) * K + (tid & 3) * 8;
  const size_t rstep = (size_t)64 * K;
  bf16* al = &As[0][0] + tid * 8;        // elem offset tid*8 (= lane*16B, wave-linear)
  bf16* bl = &Bs[0][0] + tid * 8;

  for (int k0 = 0; k0 < K; k0 += 32) {
    __syncthreads();                 // LDS consumed by all waves before overwrite
    gld_lds16(ag + k0, al);          // rows 0..63 of A-tile
    gld_lds16(ag + k0 + rstep, al + 64 * 32);   // rows 64..127
    gld_lds16(bg + k0, bl);
    gld_lds16(bg + k0 + rstep, bl + 64 * 32);
    __syncthreads();                 // vmcnt drain + visibility
    bf16x8 af[4], bfr[4];
#pragma unroll
    for (int i = 0; i < 4; ++i) {
      af[i]  = *(const bf16x8*)&As[wr + i * 16 + lrow][lgrp * 8];
      bfr[i] = *(const bf16x8*)&Bs[wc + i * 16 + lrow][lgrp * 8];
    }
#pragma unroll
    for (int mi = 0; mi < 4; ++mi)
#pragma unroll
      for (int ni = 0; ni < 4; ++ni)
        acc[mi][ni] = mfma16(af[mi], bfr[ni], acc[mi][ni]);
  }

#pragma unroll
  for (int mi = 0; mi < 4; ++mi) {
    const int rowb = brow + wr + mi * 16 + lgrp * 4;
#pragma unroll
    for (int ni = 0; ni < 4; ++ni) {
      const int col = bcol + wc + ni * 16 + lrow;
#pragma unroll
      for (int r = 0; r < 4; ++r) {
        const float v = acc[mi][ni][r];
        const int m = rowb + r;
        if (EPI == 0) {
          ((float*)Cout)[(size_t)m * N + col] = v;
        } else {
          const int bb = m >> 11, s = m & (S_ - 1);
          const int hh = col >> 6, d = col & (DH_ - 1);
          if (EPI == 1)
            ((bf16*)Cout)[((size_t)((bb * H_ + hh) * S_ + s)) * DH_ + d] = (bf16)v;
          else
            ((bf16*)Cout)[((size_t)((bb * H_ + hh) * DH_ + d)) * S_ + s] = (bf16)v;
        }
      }
    }
  }
}

// ---------------- flash attention ----------------
// grid (T/128, H, B), 256 thr = 4 waves; wave owns 32 q-rows (2 m-tiles)
__global__ __launch_bounds__(256)
void attn_kernel(const bf16* __restrict__ Q, const bf16* __restrict__ Kb,
                 const bf16* __restrict__ Vt, const float* __restrict__ tab,
                 bf16* __restrict__ Oa) {
  const int b = blockIdx.z, h = blockIdx.y;
  const int wave = threadIdx.x >> 6, lane = threadIdx.x & 63;
  const int lrow = lane & 15, lgrp = lane >> 4;
  const int q0 = blockIdx.x * 128 + wave * 32;

  const bf16* Qp = Q + (size_t)(b * H_ + h) * S_ * DH_;
  const bf16* Kp = Kb + (size_t)(b * H_ + h) * S_ * DH_;
  const bf16* Vp = Vt + (size_t)(b * H_ + h) * DH_ * S_;
  const float* th = tab + h * 4096 + 2047;

  __shared__ bf16 P_lds[4][32][72];   // per-wave, rows padded 64->72 (kills 32-bank wrap)

  bf16x8 qf[2][2];
#pragma unroll
  for (int mi = 0; mi < 2; ++mi)
#pragma unroll
    for (int kc = 0; kc < 2; ++kc)
      qf[mi][kc] = *(const bf16x8*)&Qp[(size_t)(q0 + mi * 16 + lrow) * DH_ + kc * 32 + lgrp * 8];

  float m_r[2][4], l_r[2][4];
  f32x4 o[2][4] = {};
#pragma unroll
  for (int mi = 0; mi < 2; ++mi)
#pragma unroll
    for (int r = 0; r < 4; ++r) { m_r[mi][r] = -1e30f; l_r[mi][r] = 0.f; }

  for (int s0 = 0; s0 < S_; s0 += 64) {
    f32x4 sc[2][4] = {};
#pragma unroll
    for (int kc = 0; kc < 2; ++kc) {
      bf16x8 kf[4];
#pragma unroll
      for (int st = 0; st < 4; ++st)
        kf[st] = *(const bf16x8*)&Kp[(size_t)(s0 + st * 16 + lrow) * DH_ + kc * 32 + lgrp * 8];
#pragma unroll
      for (int mi = 0; mi < 2; ++mi)
#pragma unroll
        for (int st = 0; st < 4; ++st)
          sc[mi][st] = mfma16(qf[mi][kc], kf[st], sc[mi][st]);
    }

#pragma unroll
    for (int mi = 0; mi < 2; ++mi) {
      const int tbase = q0 + mi * 16 + lgrp * 4;
      float rowmax[4] = {-1e30f, -1e30f, -1e30f, -1e30f};
#pragma unroll
      for (int st = 0; st < 4; ++st) {
        const int s = s0 + st * 16 + lrow;
#pragma unroll
        for (int r = 0; r < 4; ++r) {
          sc[mi][st][r] += th[s - (tbase + r)];
          rowmax[r] = fmaxf(rowmax[r], sc[mi][st][r]);
        }
      }
#pragma unroll
      for (int r = 0; r < 4; ++r) {
        float v = rowmax[r];
        v = fmaxf(v, __shfl_xor(v, 1));
        v = fmaxf(v, __shfl_xor(v, 2));
        v = fmaxf(v, __shfl_xor(v, 4));
        v = fmaxf(v, __shfl_xor(v, 8));
        rowmax[r] = v;
      }
      float scale[4], rowsum[4] = {0.f, 0.f, 0.f, 0.f};
#pragma unroll
      for (int r = 0; r < 4; ++r) {
        const float mn = fmaxf(m_r[mi][r], rowmax[r]);
        scale[r] = __expf(m_r[mi][r] - mn);
        m_r[mi][r] = mn;
      }
#pragma unroll
      for (int st = 0; st < 4; ++st)
#pragma unroll
        for (int r = 0; r < 4; ++r) {
          const float p = __expf(sc[mi][st][r] - m_r[mi][r]);
          sc[mi][st][r] = p;
          rowsum[r] += p;
        }
#pragma unroll
      for (int r = 0; r < 4; ++r) {
        float v = rowsum[r];
        v += __shfl_xor(v, 1);
        v += __shfl_xor(v, 2);
        v += __shfl_xor(v, 4);
        v += __shfl_xor(v, 8);
        l_r[mi][r] = l_r[mi][r] * scale[r] + v;
      }
      // P (D-layout) -> LDS, to be re-read in A-fragment layout
#pragma unroll
      for (int st = 0; st < 4; ++st)
#pragma unroll
        for (int r = 0; r < 4; ++r)
          P_lds[wave][mi * 16 + lgrp * 4 + r][st * 16 + lrow] = (bf16)sc[mi][st][r];
      // rescale running O
#pragma unroll
      for (int dt = 0; dt < 4; ++dt)
#pragma unroll
        for (int r = 0; r < 4; ++r)
          o[mi][dt][r] *= scale[r];
    }

    // PV: A = P (16 x 64 per m-tile), B = V via Vt rows (contiguous)
    bf16x8 vf[4][2];
#pragma unroll
    for (int dt = 0; dt < 4; ++dt)
#pragma unroll
      for (int kc = 0; kc < 2; ++kc)
        vf[dt][kc] = *(const bf16x8*)&Vp[(size_t)(dt * 16 + lrow) * S_ + s0 + kc * 32 + lgrp * 8];
#pragma unroll
    for (int mi = 0; mi < 2; ++mi) {
      bf16x8 pf[2];
#pragma unroll
      for (int kc = 0; kc < 2; ++kc)
        pf[kc] = *(const bf16x8*)&P_lds[wave][mi * 16 + lrow][kc * 32 + lgrp * 8];
#pragma unroll
      for (int dt = 0; dt < 4; ++dt)
#pragma unroll
        for (int kc = 0; kc < 2; ++kc)
          o[mi][dt] = mfma16(pf[kc], vf[dt][kc], o[mi][dt]);
    }
  }

#pragma unroll
  for (int mi = 0; mi < 2; ++mi)
#pragma unroll
    for (int dt = 0; dt < 4; ++dt)
#pragma unroll
      for (int r = 0; r < 4; ++r) {
        const int t = q0 + mi * 16 + lgrp * 4 + r;
        const int d = dt * 16 + lrow;
        const float v = o[mi][dt][r] / l_r[mi][r];
        Oa[((size_t)(b * S_ + t)) * D_ + h * DH_ + d] = (bf16)v;
      }
}

// ---------------- launch ----------------
extern "C" void kernel_launch(void* const* d_in, const int* in_sizes, int n_in,
                              void* d_out, int out_size, void* d_ws, size_t ws_size,
                              hipStream_t stream) {
  const float* Xq   = (const float*)d_in[0];
  const float* Xkv  = (const float*)d_in[1];
  const float* Wq   = (const float*)d_in[2];
  const float* Wk   = (const float*)d_in[3];
  const float* Wv   = (const float*)d_in[4];
  const float* Wo   = (const float*)d_in[5];
  const float* relb = (const float*)d_in[6];
  float* out = (float*)d_out;

  char* ws = (char*)d_ws;
  const size_t SZ_X = (size_t)M_ * D_ * 2;   // 16 MB
  const size_t SZ_W = (size_t)D_ * D_ * 2;   // 2 MB
  bf16* Xq_b  = (bf16*)(ws);
  bf16* Xkv_b = (bf16*)(ws + SZ_X);
  bf16* Wq_t  = (bf16*)(ws + 2 * SZ_X);
  bf16* Wk_t  = (bf16*)(ws + 2 * SZ_X + SZ_W);
  bf16* Wv_t  = (bf16*)(ws + 2 * SZ_X + 2 * SZ_W);
  bf16* Wo_t  = (bf16*)(ws + 2 * SZ_X + 3 * SZ_W);
  bf16* Qb    = (bf16*)(ws + 2 * SZ_X + 4 * SZ_W);
  bf16* Kbuf  = (bf16*)(ws + 3 * SZ_X + 4 * SZ_W);
  bf16* Vt    = (bf16*)(ws + 4 * SZ_X + 4 * SZ_W);
  bf16* Ab    = (bf16*)(ws + 5 * SZ_X + 4 * SZ_W);
  float* tab  = (float*)(ws + 6 * SZ_X + 4 * SZ_W);  // 16*4096 f32

  cast_kernel<<<8192, 256, 0, stream>>>(Xq, Xq_b);
  cast_kernel<<<8192, 256, 0, stream>>>(Xkv, Xkv_b);
  transpose_cast_kernel<<<dim3(32, 32), dim3(32, 8), 0, stream>>>(Wq, Wq_t);
  transpose_cast_kernel<<<dim3(32, 32), dim3(32, 8), 0, stream>>>(Wk, Wk_t);
  transpose_cast_kernel<<<dim3(32, 32), dim3(32, 8), 0, stream>>>(Wv, Wv_t);
  transpose_cast_kernel<<<dim3(32, 32), dim3(32, 8), 0, stream>>>(Wo, Wo_t);
  bias_table_kernel<<<256, 256, 0, stream>>>(relb, tab);

  dim3 ggrid(D_ / 128, M_ / 128);   // (8, 64)
  gemm_bt_kernel<1><<<ggrid, 256, 0, stream>>>(Xq_b, Wq_t, Qb);
  gemm_bt_kernel<1><<<ggrid, 256, 0, stream>>>(Xkv_b, Wk_t, Kbuf);
  gemm_bt_kernel<2><<<ggrid, 256, 0, stream>>>(Xkv_b, Wv_t, Vt);
  attn_kernel<<<dim3(S_ / 128, H_, B_), 256, 0, stream>>>(Qb, Kbuf, Vt, tab, Ab);
  gemm_bt_kernel<0><<<ggrid, 256, 0, stream>>>(Ab, Wo_t, out);
}

// Round 3
// 355.943 us; speedup vs baseline: 1.3074x; 1.3074x over previous
//
#include <hip/hip_runtime.h>
#include <hip/hip_bf16.h>
#include <math.h>

typedef __bf16 bf16;
typedef __attribute__((ext_vector_type(8))) __bf16 bf16x8;
typedef __attribute__((ext_vector_type(4))) __bf16 bf16x4;
typedef __attribute__((ext_vector_type(4))) float f32x4;

#define B_  4
#define S_  2048
#define D_  1024
#define H_  16
#define DH_ 64
#define M_  (B_ * S_)   // 8192

static __device__ __forceinline__ f32x4 mfma16(bf16x8 a, bf16x8 b, f32x4 c) {
  return __builtin_amdgcn_mfma_f32_16x16x32_bf16(a, b, c, 0, 0, 0);
}

static __device__ __forceinline__ void gld_lds16(const bf16* g, bf16* l) {
  __builtin_amdgcn_global_load_lds(
      (const __attribute__((address_space(1))) void*)g,
      (__attribute__((address_space(3))) void*)l, 16, 0, 0);
}

// ---------------- f32 -> bf16 cast (4 elems/thread) ----------------
__global__ __launch_bounds__(256)
void cast_kernel(const float* __restrict__ in, bf16* __restrict__ out) {
  size_t i = ((size_t)blockIdx.x * 256 + threadIdx.x) * 4;
  float4 v = *(const float4*)(in + i);
  bf16x4 o = {(bf16)v.x, (bf16)v.y, (bf16)v.z, (bf16)v.w};
  *(bf16x4*)(out + i) = o;
}

// ---------------- transpose+cast: out[n][k] = bf16(in[k][n]), 1024x1024 ----------------
__global__ __launch_bounds__(256)
void transpose_cast_kernel(const float* __restrict__ in, bf16* __restrict__ out) {
  __shared__ float tile[32][33];
  int n0 = blockIdx.x * 32, k0 = blockIdx.y * 32;
  int tx = threadIdx.x, ty = threadIdx.y;
#pragma unroll
  for (int j = 0; j < 32; j += 8)
    tile[ty + j][tx] = in[(size_t)(k0 + ty + j) * D_ + n0 + tx];
  __syncthreads();
#pragma unroll
  for (int j = 0; j < 32; j += 8)
    out[(size_t)(n0 + ty + j) * D_ + k0 + tx] = (bf16)tile[tx][ty + j];
}

// ---------------- bias table: tab[h*4096 + (s-t+2047)] ----------------
__global__ __launch_bounds__(256)
void bias_table_kernel(const float* __restrict__ rel_bias, float* __restrict__ tab) {
  int i = blockIdx.x * 256 + threadIdx.x;   // 16*4096 entries
  int h = i >> 12, dp = i & 4095;
  int rel = dp - 2047;                       // rel = s - t
  int bucket = (rel > 0) ? 16 : 0;
  int rp = rel < 0 ? -rel : rel;
  if (rp < 8) {
    bucket += rp;
  } else {
    // ln(rp/8)/ln(16)*8 == 2*log2(rp/8); exact at rp = 16,32,64,128 boundaries
    int large = 8 + (int)(2.0f * __log2f((float)rp * 0.125f));
    bucket += (large < 15 ? large : 15);
  }
  tab[i] = rel_bias[bucket * H_ + h];
}

// ---------------- GEMM: C[MxN] = A[MxK] * Bt[NxK]^T  (m97 structure) ----------------
template<int EPI>
__global__ __launch_bounds__(256)
void gemm_bt_kernel(const bf16* __restrict__ A, const bf16* __restrict__ Bt,
                    void* __restrict__ Cout) {
  const int K = D_, N = D_;
  __shared__ bf16 As[128][32];
  __shared__ bf16 Bs[128][32];
  const int tid = threadIdx.x;
  const int brow = blockIdx.y * 128, bcol = blockIdx.x * 128;
  const int wave = tid >> 6, lane = tid & 63;
  const int wr = (wave >> 1) * 64, wc = (wave & 1) * 64;
  const int lrow = lane & 15, lgrp = lane >> 4;

  f32x4 acc[4][4] = {};

  const bf16* ag = A + (size_t)(brow + (tid >> 2)) * K + (tid & 3) * 8;
  const bf16* bg = Bt + (size_t)(bcol + (tid >> 2)) * K + (tid & 3) * 8;
  const size_t rstep = (size_t)64 * K;
  bf16* al = &As[0][0] + tid * 8;
  bf16* bl = &Bs[0][0] + tid * 8;

  for (int k0 = 0; k0 < K; k0 += 32) {
    __syncthreads();
    gld_lds16(ag + k0, al);
    gld_lds16(ag + k0 + rstep, al + 64 * 32);
    gld_lds16(bg + k0, bl);
    gld_lds16(bg + k0 + rstep, bl + 64 * 32);
    __syncthreads();
    bf16x8 af[4], bfr[4];
#pragma unroll
    for (int i = 0; i < 4; ++i) {
      af[i]  = *(const bf16x8*)&As[wr + i * 16 + lrow][lgrp * 8];
      bfr[i] = *(const bf16x8*)&Bs[wc + i * 16 + lrow][lgrp * 8];
    }
#pragma unroll
    for (int mi = 0; mi < 4; ++mi)
#pragma unroll
      for (int ni = 0; ni < 4; ++ni)
        acc[mi][ni] = mfma16(af[mi], bfr[ni], acc[mi][ni]);
  }

#pragma unroll
  for (int mi = 0; mi < 4; ++mi) {
    const int rowb = brow + wr + mi * 16 + lgrp * 4;
#pragma unroll
    for (int ni = 0; ni < 4; ++ni) {
      const int col = bcol + wc + ni * 16 + lrow;
#pragma unroll
      for (int r = 0; r < 4; ++r) {
        const float v = acc[mi][ni][r];
        const int m = rowb + r;
        if (EPI == 0) {
          ((float*)Cout)[(size_t)m * N + col] = v;
        } else {
          const int bb = m >> 11, s = m & (S_ - 1);
          const int hh = col >> 6, d = col & (DH_ - 1);
          if (EPI == 1)
            ((bf16*)Cout)[((size_t)((bb * H_ + hh) * S_ + s)) * DH_ + d] = (bf16)v;
          else
            ((bf16*)Cout)[((size_t)((bb * H_ + hh) * DH_ + d)) * S_ + s] = (bf16)v;
        }
      }
    }
  }
}

// ---------------- flash attention v2 ----------------
// 1024 blocks (XCD-swizzled), 4 waves; wave owns 32 q-rows.
// K/V tiles staged in LDS (XOR-swizzled via pre-swizzled global src), bias window in LDS.
__global__ __launch_bounds__(256, 3)
void attn_kernel(const bf16* __restrict__ Q, const bf16* __restrict__ Kb,
                 const bf16* __restrict__ Vt, const float* __restrict__ tab,
                 bf16* __restrict__ Oa) {
  __shared__ bf16 Ks[64 * 64];        // [s_local][d], rows 128B, XOR-swizzled
  __shared__ bf16 Vs[64 * 64];        // [d][s_local], rows 128B, XOR-swizzled
  __shared__ float biasw[2176];       // bias window for this block's t-range
  __shared__ bf16 P_lds[4][32][72];   // per-wave P, padded rows

  const int bid = blockIdx.x;
  const int w = ((bid & 7) << 7) + (bid >> 3);   // XCD x owns 8 full (b,h) panels
  const int qt = w & 15, h = (w >> 4) & 15, b = w >> 8;
  const int tid = threadIdx.x;
  const int wave = tid >> 6, lane = tid & 63;
  const int lrow = lane & 15, lgrp = lane >> 4;
  const int q0b = qt * 128;
  const int q0 = q0b + wave * 32;

  const bf16* Qp = Q + (size_t)(b * H_ + h) * S_ * DH_;
  const bf16* Kp = Kb + (size_t)(b * H_ + h) * S_ * DH_;
  const bf16* Vp = Vt + (size_t)(b * H_ + h) * DH_ * S_;
  const float* tabh = tab + h * 4096;

  // stage bias window: biasw[u] = tab_h[(1920 - q0b) + u], u in [0,2176)
  const int Wb = 1920 - q0b;
  for (int u = tid; u < 2176; u += 256) biasw[u] = tabh[Wb + u];

  // staging source precompute (thread tid stages rows srow and srow+32, 16B each)
  const int srow = tid >> 3;                                     // 0..31
  const int ce = ((((tid & 7) << 4) ^ ((srow & 7) << 4)) >> 1);  // swizzled col (elems)
  const bf16* ksrc = Kp + (size_t)srow * DH_ + ce;
  const bf16* vsrc = Vp + (size_t)srow * S_ + ce;
  bf16* kdst = Ks + tid * 8;
  bf16* vdst = Vs + tid * 8;
  const int swz = (lrow & 7) << 4;   // read-side byte XOR (row&7 == lrow&7)

  // Q fragments (registers, once)
  bf16x8 qf[2][2];
#pragma unroll
  for (int mi = 0; mi < 2; ++mi)
#pragma unroll
    for (int kc = 0; kc < 2; ++kc)
      qf[mi][kc] = *(const bf16x8*)&Qp[(size_t)(q0 + mi * 16 + lrow) * DH_ + kc * 32 + lgrp * 8];

  float m_r[2][4], l_r[2][4];
  f32x4 o[2][4] = {};
#pragma unroll
  for (int mi = 0; mi < 2; ++mi)
#pragma unroll
    for (int r = 0; r < 4; ++r) { m_r[mi][r] = -1e30f; l_r[mi][r] = 0.f; }

  const int cb = 127 - wave * 32 - lgrp * 4 + lrow;   // bias idx helper

  for (int s0 = 0; s0 < S_; s0 += 64) {
    __syncthreads();                       // prior tile's LDS reads complete
    gld_lds16(ksrc + (size_t)s0 * DH_, kdst);
    gld_lds16(ksrc + (size_t)(s0 + 32) * DH_, kdst + 2048);
    gld_lds16(vsrc + s0, vdst);
    gld_lds16(vsrc + 32 * S_ + s0, vdst + 2048);
    __syncthreads();                       // staged data visible (vmcnt drained)

    // QK^T from swizzled LDS
    f32x4 sc[2][4] = {};
#pragma unroll
    for (int kc = 0; kc < 2; ++kc) {
      bf16x8 kf[4];
#pragma unroll
      for (int st = 0; st < 4; ++st)
        kf[st] = *(const bf16x8*)((const char*)Ks +
                  (st * 16 + lrow) * 128 + (((kc << 6) + (lgrp << 4)) ^ swz));
#pragma unroll
      for (int mi = 0; mi < 2; ++mi)
#pragma unroll
        for (int st = 0; st < 4; ++st)
          sc[mi][st] = mfma16(qf[mi][kc], kf[st], sc[mi][st]);
    }

#pragma unroll
    for (int mi = 0; mi < 2; ++mi) {
      float rowmax[4] = {-1e30f, -1e30f, -1e30f, -1e30f};
#pragma unroll
      for (int st = 0; st < 4; ++st) {
        const int bidx = s0 + st * 16 + cb - mi * 16;   // - r below
#pragma unroll
        for (int r = 0; r < 4; ++r) {
          sc[mi][st][r] += biasw[bidx - r];
          rowmax[r] = fmaxf(rowmax[r], sc[mi][st][r]);
        }
      }
#pragma unroll
      for (int r = 0; r < 4; ++r) {
        float v = rowmax[r];
        v = fmaxf(v, __shfl_xor(v, 1));
        v = fmaxf(v, __shfl_xor(v, 2));
        v = fmaxf(v, __shfl_xor(v, 4));
        v = fmaxf(v, __shfl_xor(v, 8));
        rowmax[r] = v;
      }
      float scale[4], rowsum[4] = {0.f, 0.f, 0.f, 0.f};
#pragma unroll
      for (int r = 0; r < 4; ++r) {
        const float mn = fmaxf(m_r[mi][r], rowmax[r]);
        scale[r] = __expf(m_r[mi][r] - mn);
        m_r[mi][r] = mn;
      }
#pragma unroll
      for (int st = 0; st < 4; ++st)
#pragma unroll
        for (int r = 0; r < 4; ++r) {
          const float p = __expf(sc[mi][st][r] - m_r[mi][r]);
          sc[mi][st][r] = p;
          rowsum[r] += p;
        }
#pragma unroll
      for (int r = 0; r < 4; ++r) {
        float v = rowsum[r];
        v += __shfl_xor(v, 1);
        v += __shfl_xor(v, 2);
        v += __shfl_xor(v, 4);
        v += __shfl_xor(v, 8);
        l_r[mi][r] = l_r[mi][r] * scale[r] + v;
      }
#pragma unroll
      for (int st = 0; st < 4; ++st)
#pragma unroll
        for (int r = 0; r < 4; ++r)
          P_lds[wave][mi * 16 + lgrp * 4 + r][st * 16 + lrow] = (bf16)sc[mi][st][r];
#pragma unroll
      for (int dt = 0; dt < 4; ++dt)
#pragma unroll
        for (int r = 0; r < 4; ++r)
          o[mi][dt][r] *= scale[r];
    }

    // PV from swizzled Vs
    bf16x8 pf[2][2];
#pragma unroll
    for (int mi = 0; mi < 2; ++mi)
#pragma unroll
      for (int kc = 0; kc < 2; ++kc)
        pf[mi][kc] = *(const bf16x8*)&P_lds[wave][mi * 16 + lrow][kc * 32 + lgrp * 8];
#pragma unroll
    for (int dt = 0; dt < 4; ++dt) {
      bf16x8 vf0 = *(const bf16x8*)((const char*)Vs +
                    (dt * 16 + lrow) * 128 + (((0 << 6) + (lgrp << 4)) ^ swz));
      bf16x8 vf1 = *(const bf16x8*)((const char*)Vs +
                    (dt * 16 + lrow) * 128 + (((1 << 6) + (lgrp << 4)) ^ swz));
#pragma unroll
      for (int mi = 0; mi < 2; ++mi) {
        o[mi][dt] = mfma16(pf[mi][0], vf0, o[mi][dt]);
        o[mi][dt] = mfma16(pf[mi][1], vf1, o[mi][dt]);
      }
    }
  }

#pragma unroll
  for (int mi = 0; mi < 2; ++mi)
#pragma unroll
    for (int dt = 0; dt < 4; ++dt)
#pragma unroll
      for (int r = 0; r < 4; ++r) {
        const int t = q0 + mi * 16 + lgrp * 4 + r;
        const int d = dt * 16 + lrow;
        const float v = o[mi][dt][r] / l_r[mi][r];
        Oa[((size_t)(b * S_ + t)) * D_ + h * DH_ + d] = (bf16)v;
      }
}

// ---------------- launch ----------------
extern "C" void kernel_launch(void* const* d_in, const int* in_sizes, int n_in,
                              void* d_out, int out_size, void* d_ws, size_t ws_size,
                              hipStream_t stream) {
  const float* Xq   = (const float*)d_in[0];
  const float* Xkv  = (const float*)d_in[1];
  const float* Wq   = (const float*)d_in[2];
  const float* Wk   = (const float*)d_in[3];
  const float* Wv   = (const float*)d_in[4];
  const float* Wo   = (const float*)d_in[5];
  const float* relb = (const float*)d_in[6];
  float* out = (float*)d_out;

  char* ws = (char*)d_ws;
  const size_t SZ_X = (size_t)M_ * D_ * 2;   // 16 MB
  const size_t SZ_W = (size_t)D_ * D_ * 2;   // 2 MB
  bf16* Xq_b  = (bf16*)(ws);
  bf16* Xkv_b = (bf16*)(ws + SZ_X);
  bf16* Wq_t  = (bf16*)(ws + 2 * SZ_X);
  bf16* Wk_t  = (bf16*)(ws + 2 * SZ_X + SZ_W);
  bf16* Wv_t  = (bf16*)(ws + 2 * SZ_X + 2 * SZ_W);
  bf16* Wo_t  = (bf16*)(ws + 2 * SZ_X + 3 * SZ_W);
  bf16* Qb    = (bf16*)(ws + 2 * SZ_X + 4 * SZ_W);
  bf16* Kbuf  = (bf16*)(ws + 3 * SZ_X + 4 * SZ_W);
  bf16* Vt    = (bf16*)(ws + 4 * SZ_X + 4 * SZ_W);
  bf16* Ab    = (bf16*)(ws + 5 * SZ_X + 4 * SZ_W);
  float* tab  = (float*)(ws + 6 * SZ_X + 4 * SZ_W);  // 16*4096 f32

  cast_kernel<<<8192, 256, 0, stream>>>(Xq, Xq_b);
  cast_kernel<<<8192, 256, 0, stream>>>(Xkv, Xkv_b);
  transpose_cast_kernel<<<dim3(32, 32), dim3(32, 8), 0, stream>>>(Wq, Wq_t);
  transpose_cast_kernel<<<dim3(32, 32), dim3(32, 8), 0, stream>>>(Wk, Wk_t);
  transpose_cast_kernel<<<dim3(32, 32), dim3(32, 8), 0, stream>>>(Wv, Wv_t);
  transpose_cast_kernel<<<dim3(32, 32), dim3(32, 8), 0, stream>>>(Wo, Wo_t);
  bias_table_kernel<<<256, 256, 0, stream>>>(relb, tab);

  dim3 ggrid(D_ / 128, M_ / 128);   // (8, 64)
  gemm_bt_kernel<1><<<ggrid, 256, 0, stream>>>(Xq_b, Wq_t, Qb);
  gemm_bt_kernel<1><<<ggrid, 256, 0, stream>>>(Xkv_b, Wk_t, Kbuf);
  gemm_bt_kernel<2><<<ggrid, 256, 0, stream>>>(Xkv_b, Wv_t, Vt);
  attn_kernel<<<1024, 256, 0, stream>>>(Qb, Kbuf, Vt, tab, Ab);
  gemm_bt_kernel<0><<<ggrid, 256, 0, stream>>>(Ab, Wo_t, out);
}

// Round 4
// 347.118 us; speedup vs baseline: 1.3406x; 1.0254x over previous
//
#include <hip/hip_runtime.h>
#include <hip/hip_bf16.h>
#include <math.h>

typedef __bf16 bf16;
typedef __attribute__((ext_vector_type(8))) __bf16 bf16x8;
typedef __attribute__((ext_vector_type(4))) __bf16 bf16x4;
typedef __attribute__((ext_vector_type(4))) float f32x4;

#define B_  4
#define S_  2048
#define D_  1024
#define H_  16
#define DH_ 64
#define M_  (B_ * S_)   // 8192

static __device__ __forceinline__ f32x4 mfma16(bf16x8 a, bf16x8 b, f32x4 c) {
  return __builtin_amdgcn_mfma_f32_16x16x32_bf16(a, b, c, 0, 0, 0);
}

static __device__ __forceinline__ void gld_lds16(const bf16* g, bf16* l) {
  __builtin_amdgcn_global_load_lds(
      (const __attribute__((address_space(1))) void*)g,
      (__attribute__((address_space(3))) void*)l, 16, 0, 0);
}

// ---------------- f32 -> bf16 cast (4 elems/thread) ----------------
__global__ __launch_bounds__(256)
void cast_kernel(const float* __restrict__ in, bf16* __restrict__ out) {
  size_t i = ((size_t)blockIdx.x * 256 + threadIdx.x) * 4;
  float4 v = *(const float4*)(in + i);
  bf16x4 o = {(bf16)v.x, (bf16)v.y, (bf16)v.z, (bf16)v.w};
  *(bf16x4*)(out + i) = o;
}

// ---------------- transpose+cast: out[n][k] = bf16(in[k][n]), 1024x1024 ----------------
__global__ __launch_bounds__(256)
void transpose_cast_kernel(const float* __restrict__ in, bf16* __restrict__ out) {
  __shared__ float tile[32][33];
  int n0 = blockIdx.x * 32, k0 = blockIdx.y * 32;
  int tx = threadIdx.x, ty = threadIdx.y;
#pragma unroll
  for (int j = 0; j < 32; j += 8)
    tile[ty + j][tx] = in[(size_t)(k0 + ty + j) * D_ + n0 + tx];
  __syncthreads();
#pragma unroll
  for (int j = 0; j < 32; j += 8)
    out[(size_t)(n0 + ty + j) * D_ + k0 + tx] = (bf16)tile[tx][ty + j];
}

// ---------------- bias table: tab[h*4096 + (s-t+2047)] ----------------
__global__ __launch_bounds__(256)
void bias_table_kernel(const float* __restrict__ rel_bias, float* __restrict__ tab) {
  int i = blockIdx.x * 256 + threadIdx.x;   // 16*4096 entries
  int h = i >> 12, dp = i & 4095;
  int rel = dp - 2047;                       // rel = s - t
  int bucket = (rel > 0) ? 16 : 0;
  int rp = rel < 0 ? -rel : rel;
  if (rp < 8) {
    bucket += rp;
  } else {
    // ln(rp/8)/ln(16)*8 == 2*log2(rp/8); exact at rp = 16,32,64,128 boundaries
    int large = 8 + (int)(2.0f * __log2f((float)rp * 0.125f));
    bucket += (large < 15 ? large : 15);
  }
  tab[i] = rel_bias[bucket * H_ + h];
}

// ---------------- GEMM: C[MxN] = A[MxK] * Bt[NxK]^T  (m97 structure) ----------------
template<int EPI>
__global__ __launch_bounds__(256)
void gemm_bt_kernel(const bf16* __restrict__ A, const bf16* __restrict__ Bt,
                    void* __restrict__ Cout) {
  const int K = D_, N = D_;
  __shared__ bf16 As[128][32];
  __shared__ bf16 Bs[128][32];
  const int tid = threadIdx.x;
  const int brow = blockIdx.y * 128, bcol = blockIdx.x * 128;
  const int wave = tid >> 6, lane = tid & 63;
  const int wr = (wave >> 1) * 64, wc = (wave & 1) * 64;
  const int lrow = lane & 15, lgrp = lane >> 4;

  f32x4 acc[4][4] = {};

  const bf16* ag = A + (size_t)(brow + (tid >> 2)) * K + (tid & 3) * 8;
  const bf16* bg = Bt + (size_t)(bcol + (tid >> 2)) * K + (tid & 3) * 8;
  const size_t rstep = (size_t)64 * K;
  bf16* al = &As[0][0] + tid * 8;
  bf16* bl = &Bs[0][0] + tid * 8;

  for (int k0 = 0; k0 < K; k0 += 32) {
    __syncthreads();
    gld_lds16(ag + k0, al);
    gld_lds16(ag + k0 + rstep, al + 64 * 32);
    gld_lds16(bg + k0, bl);
    gld_lds16(bg + k0 + rstep, bl + 64 * 32);
    __syncthreads();
    bf16x8 af[4], bfr[4];
#pragma unroll
    for (int i = 0; i < 4; ++i) {
      af[i]  = *(const bf16x8*)&As[wr + i * 16 + lrow][lgrp * 8];
      bfr[i] = *(const bf16x8*)&Bs[wc + i * 16 + lrow][lgrp * 8];
    }
#pragma unroll
    for (int mi = 0; mi < 4; ++mi)
#pragma unroll
      for (int ni = 0; ni < 4; ++ni)
        acc[mi][ni] = mfma16(af[mi], bfr[ni], acc[mi][ni]);
  }

#pragma unroll
  for (int mi = 0; mi < 4; ++mi) {
    const int rowb = brow + wr + mi * 16 + lgrp * 4;
#pragma unroll
    for (int ni = 0; ni < 4; ++ni) {
      const int col = bcol + wc + ni * 16 + lrow;
#pragma unroll
      for (int r = 0; r < 4; ++r) {
        const float v = acc[mi][ni][r];
        const int m = rowb + r;
        if (EPI == 0) {
          ((float*)Cout)[(size_t)m * N + col] = v;
        } else {
          const int bb = m >> 11, s = m & (S_ - 1);
          const int hh = col >> 6, d = col & (DH_ - 1);
          if (EPI == 1)
            ((bf16*)Cout)[((size_t)((bb * H_ + hh) * S_ + s)) * DH_ + d] = (bf16)v;
          else
            ((bf16*)Cout)[((size_t)((bb * H_ + hh) * DH_ + d)) * S_ + s] = (bf16)v;
        }
      }
    }
  }
}

// ---------------- flash attention v3 ----------------
// 1024 blocks (XCD-swizzled), 512 thr = 8 waves; wave owns 16 q-rows.
// K/V double-buffered in LDS (XOR-swizzled), issue-early staging, bias from L1.
__global__ __launch_bounds__(512, 6)
void attn_kernel(const bf16* __restrict__ Q, const bf16* __restrict__ Kb,
                 const bf16* __restrict__ Vt, const float* __restrict__ tab,
                 bf16* __restrict__ Oa) {
  __shared__ bf16 Ks[2][64 * 64];     // [s_local][d], rows 128B, XOR-swizzled
  __shared__ bf16 Vs[2][64 * 64];     // [d][s_local], rows 128B, XOR-swizzled
  __shared__ bf16 P_lds[8][16][72];   // per-wave P, padded rows

  const int bid = blockIdx.x;
  const int w = ((bid & 7) << 7) + (bid >> 3);   // XCD x owns 8 full (b,h) panels
  const int qt = w & 15, h = (w >> 4) & 15, b = w >> 8;
  const int tid = threadIdx.x;
  const int wave = tid >> 6, lane = tid & 63;
  const int lrow = lane & 15, lgrp = lane >> 4;
  const int q0 = qt * 128 + wave * 16;

  const bf16* Qp = Q + (size_t)(b * H_ + h) * S_ * DH_;
  const bf16* Kp = Kb + (size_t)(b * H_ + h) * S_ * DH_;
  const bf16* Vp = Vt + (size_t)(b * H_ + h) * DH_ * S_;
  // bias ptr: tb2[s0 + st*16 - r] = tab_h[(s - t) + 2047]   (L1-resident 16KB table)
  const float* tb2 = tab + h * 4096 + 2047 - q0 - lgrp * 4 + lrow;

  // staging: thread tid stages row tid>>3, 16B chunk (tid&7), source pre-XOR-swizzled
  const int srow = tid >> 3;                                     // 0..63
  const int ce = ((((tid & 7) << 4) ^ ((srow & 7) << 4)) >> 1);  // swizzled col (elems)
  const bf16* ksrc = Kp + (size_t)srow * DH_ + ce;
  const bf16* vsrc = Vp + (size_t)srow * S_ + ce;
  bf16* kdst0 = &Ks[0][0] + tid * 8;
  bf16* vdst0 = &Vs[0][0] + tid * 8;
  const int swz = (lrow & 7) << 4;   // read-side byte XOR

  // Q fragments (registers, once)
  bf16x8 qf[2];
#pragma unroll
  for (int kc = 0; kc < 2; ++kc)
    qf[kc] = *(const bf16x8*)&Qp[(size_t)(q0 + lrow) * DH_ + kc * 32 + lgrp * 8];

  float m_r[4], l_r[4];
  f32x4 o[4] = {};
#pragma unroll
  for (int r = 0; r < 4; ++r) { m_r[r] = -1e30f; l_r[r] = 0.f; }

  // prologue: stage tile 0 into buf 0
  gld_lds16(ksrc, kdst0);
  gld_lds16(vsrc, vdst0);
  __syncthreads();

  for (int s0 = 0; s0 < S_; s0 += 64) {
    const int buf = (s0 >> 6) & 1;
    // issue-early: stage next tile into other buffer (latency hides under compute)
    if (s0 + 64 < S_) {
      const int nb = buf ^ 1;
      gld_lds16(ksrc + (size_t)(s0 + 64) * DH_, kdst0 + nb * 4096);
      gld_lds16(vsrc + (s0 + 64), vdst0 + nb * 4096);
    }
    const char* kb = (const char*)&Ks[buf][0];
    const char* vb = (const char*)&Vs[buf][0];

    // QK^T from swizzled LDS
    f32x4 sc[4] = {};
#pragma unroll
    for (int kc = 0; kc < 2; ++kc) {
      bf16x8 kf[4];
#pragma unroll
      for (int st = 0; st < 4; ++st)
        kf[st] = *(const bf16x8*)(kb + (st * 16 + lrow) * 128 +
                                  (((kc << 6) + (lgrp << 4)) ^ swz));
#pragma unroll
      for (int st = 0; st < 4; ++st)
        sc[st] = mfma16(qf[kc], kf[st], sc[st]);
    }

    // bias + online softmax (16 rows per wave)
    float rowmax[4] = {-1e30f, -1e30f, -1e30f, -1e30f};
#pragma unroll
    for (int st = 0; st < 4; ++st) {
      const float* tbs = tb2 + s0 + st * 16;
#pragma unroll
      for (int r = 0; r < 4; ++r) {
        sc[st][r] += tbs[-r];
        rowmax[r] = fmaxf(rowmax[r], sc[st][r]);
      }
    }
#pragma unroll
    for (int r = 0; r < 4; ++r) {
      float v = rowmax[r];
      v = fmaxf(v, __shfl_xor(v, 1));
      v = fmaxf(v, __shfl_xor(v, 2));
      v = fmaxf(v, __shfl_xor(v, 4));
      v = fmaxf(v, __shfl_xor(v, 8));
      rowmax[r] = v;
    }
    float scale[4], rowsum[4] = {0.f, 0.f, 0.f, 0.f};
#pragma unroll
    for (int r = 0; r < 4; ++r) {
      const float mn = fmaxf(m_r[r], rowmax[r]);
      scale[r] = __expf(m_r[r] - mn);
      m_r[r] = mn;
    }
#pragma unroll
    for (int st = 0; st < 4; ++st)
#pragma unroll
      for (int r = 0; r < 4; ++r) {
        const float p = __expf(sc[st][r] - m_r[r]);
        sc[st][r] = p;
        rowsum[r] += p;
      }
#pragma unroll
    for (int r = 0; r < 4; ++r) {
      float v = rowsum[r];
      v += __shfl_xor(v, 1);
      v += __shfl_xor(v, 2);
      v += __shfl_xor(v, 4);
      v += __shfl_xor(v, 8);
      l_r[r] = l_r[r] * scale[r] + v;
    }
    // P (D-layout) -> per-wave LDS, re-read in A-fragment layout
#pragma unroll
    for (int st = 0; st < 4; ++st)
#pragma unroll
      for (int r = 0; r < 4; ++r)
        P_lds[wave][lgrp * 4 + r][st * 16 + lrow] = (bf16)sc[st][r];
    // rescale running O
#pragma unroll
    for (int dt = 0; dt < 4; ++dt)
#pragma unroll
      for (int r = 0; r < 4; ++r)
        o[dt][r] *= scale[r];

    // PV from swizzled Vs
    bf16x8 pf[2];
#pragma unroll
    for (int kc = 0; kc < 2; ++kc)
      pf[kc] = *(const bf16x8*)&P_lds[wave][lrow][kc * 32 + lgrp * 8];
#pragma unroll
    for (int dt = 0; dt < 4; ++dt) {
      bf16x8 vf0 = *(const bf16x8*)(vb + (dt * 16 + lrow) * 128 + ((lgrp << 4) ^ swz));
      bf16x8 vf1 = *(const bf16x8*)(vb + (dt * 16 + lrow) * 128 + ((64 + (lgrp << 4)) ^ swz));
      o[dt] = mfma16(pf[0], vf0, o[dt]);
      o[dt] = mfma16(pf[1], vf1, o[dt]);
    }

    __syncthreads();   // drains vmcnt (publishes next buf) + lgkm (P_lds/K/V reads done)
  }

#pragma unroll
  for (int dt = 0; dt < 4; ++dt)
#pragma unroll
    for (int r = 0; r < 4; ++r) {
      const int t = q0 + lgrp * 4 + r;
      const int d = dt * 16 + lrow;
      const float v = o[dt][r] / l_r[r];
      Oa[((size_t)(b * S_ + t)) * D_ + h * DH_ + d] = (bf16)v;
    }
}

// ---------------- launch ----------------
extern "C" void kernel_launch(void* const* d_in, const int* in_sizes, int n_in,
                              void* d_out, int out_size, void* d_ws, size_t ws_size,
                              hipStream_t stream) {
  const float* Xq   = (const float*)d_in[0];
  const float* Xkv  = (const float*)d_in[1];
  const float* Wq   = (const float*)d_in[2];
  const float* Wk   = (const float*)d_in[3];
  const float* Wv   = (const float*)d_in[4];
  const float* Wo   = (const float*)d_in[5];
  const float* relb = (const float*)d_in[6];
  float* out = (float*)d_out;

  char* ws = (char*)d_ws;
  const size_t SZ_X = (size_t)M_ * D_ * 2;   // 16 MB
  const size_t SZ_W = (size_t)D_ * D_ * 2;   // 2 MB
  bf16* Xq_b  = (bf16*)(ws);
  bf16* Xkv_b = (bf16*)(ws + SZ_X);
  bf16* Wq_t  = (bf16*)(ws + 2 * SZ_X);
  bf16* Wk_t  = (bf16*)(ws + 2 * SZ_X + SZ_W);
  bf16* Wv_t  = (bf16*)(ws + 2 * SZ_X + 2 * SZ_W);
  bf16* Wo_t  = (bf16*)(ws + 2 * SZ_X + 3 * SZ_W);
  bf16* Qb    = (bf16*)(ws + 2 * SZ_X + 4 * SZ_W);
  bf16* Kbuf  = (bf16*)(ws + 3 * SZ_X + 4 * SZ_W);
  bf16* Vt    = (bf16*)(ws + 4 * SZ_X + 4 * SZ_W);
  bf16* Ab    = (bf16*)(ws + 5 * SZ_X + 4 * SZ_W);
  float* tab  = (float*)(ws + 6 * SZ_X + 4 * SZ_W);  // 16*4096 f32

  cast_kernel<<<8192, 256, 0, stream>>>(Xq, Xq_b);
  cast_kernel<<<8192, 256, 0, stream>>>(Xkv, Xkv_b);
  transpose_cast_kernel<<<dim3(32, 32), dim3(32, 8), 0, stream>>>(Wq, Wq_t);
  transpose_cast_kernel<<<dim3(32, 32), dim3(32, 8), 0, stream>>>(Wk, Wk_t);
  transpose_cast_kernel<<<dim3(32, 32), dim3(32, 8), 0, stream>>>(Wv, Wv_t);
  transpose_cast_kernel<<<dim3(32, 32), dim3(32, 8), 0, stream>>>(Wo, Wo_t);
  bias_table_kernel<<<256, 256, 0, stream>>>(relb, tab);

  dim3 ggrid(D_ / 128, M_ / 128);   // (8, 64)
  gemm_bt_kernel<1><<<ggrid, 256, 0, stream>>>(Xq_b, Wq_t, Qb);
  gemm_bt_kernel<1><<<ggrid, 256, 0, stream>>>(Xkv_b, Wk_t, Kbuf);
  gemm_bt_kernel<2><<<ggrid, 256, 0, stream>>>(Xkv_b, Wv_t, Vt);
  attn_kernel<<<1024, 512, 0, stream>>>(Qb, Kbuf, Vt, tab, Ab);
  gemm_bt_kernel<0><<<ggrid, 256, 0, stream>>>(Ab, Wo_t, out);
}

// Round 5
// 317.884 us; speedup vs baseline: 1.4639x; 1.0920x over previous
//
#include <hip/hip_runtime.h>
#include <hip/hip_bf16.h>
#include <math.h>

typedef __bf16 bf16;
typedef __attribute__((ext_vector_type(8))) __bf16 bf16x8;
typedef __attribute__((ext_vector_type(4))) __bf16 bf16x4;
typedef __attribute__((ext_vector_type(4))) float f32x4;
typedef __attribute__((ext_vector_type(4), aligned(4))) float f32x4u;  // unaligned vec load

#define B_  4
#define S_  2048
#define D_  1024
#define H_  16
#define DH_ 64
#define M_  (B_ * S_)   // 8192
#define LOG2E 1.44269504088896f

static __device__ __forceinline__ f32x4 mfma16(bf16x8 a, bf16x8 b, f32x4 c) {
  return __builtin_amdgcn_mfma_f32_16x16x32_bf16(a, b, c, 0, 0, 0);
}

static __device__ __forceinline__ void gld_lds16(const bf16* g, bf16* l) {
  __builtin_amdgcn_global_load_lds(
      (const __attribute__((address_space(1))) void*)g,
      (__attribute__((address_space(3))) void*)l, 16, 0, 0);
}

// ---------------- f32 -> bf16 cast (4 elems/thread) ----------------
__global__ __launch_bounds__(256)
void cast_kernel(const float* __restrict__ in, bf16* __restrict__ out) {
  size_t i = ((size_t)blockIdx.x * 256 + threadIdx.x) * 4;
  float4 v = *(const float4*)(in + i);
  bf16x4 o = {(bf16)v.x, (bf16)v.y, (bf16)v.z, (bf16)v.w};
  *(bf16x4*)(out + i) = o;
}

// ---------------- transpose+cast: out[n][k] = bf16(in[k][n]), 1024x1024 ----------------
__global__ __launch_bounds__(256)
void transpose_cast_kernel(const float* __restrict__ in, bf16* __restrict__ out) {
  __shared__ float tile[32][33];
  int n0 = blockIdx.x * 32, k0 = blockIdx.y * 32;
  int tx = threadIdx.x, ty = threadIdx.y;
#pragma unroll
  for (int j = 0; j < 32; j += 8)
    tile[ty + j][tx] = in[(size_t)(k0 + ty + j) * D_ + n0 + tx];
  __syncthreads();
#pragma unroll
  for (int j = 0; j < 32; j += 8)
    out[(size_t)(n0 + ty + j) * D_ + k0 + tx] = (bf16)tile[tx][ty + j];
}

// ---------------- bias table (exp2 domain): tab[h*4096 + (s-t+2047)] = bias*log2e ----------------
__global__ __launch_bounds__(256)
void bias_table_kernel(const float* __restrict__ rel_bias, float* __restrict__ tab) {
  int i = blockIdx.x * 256 + threadIdx.x;   // 16*4096 entries
  int h = i >> 12, dp = i & 4095;
  int rel = dp - 2047;                       // rel = s - t
  int bucket = (rel > 0) ? 16 : 0;
  int rp = rel < 0 ? -rel : rel;
  if (rp < 8) {
    bucket += rp;
  } else {
    // ln(rp/8)/ln(16)*8 == 2*log2(rp/8); exact at rp = 16,32,64,128 boundaries
    int large = 8 + (int)(2.0f * __log2f((float)rp * 0.125f));
    bucket += (large < 15 ? large : 15);
  }
  tab[i] = rel_bias[bucket * H_ + h] * LOG2E;
}

// ---------------- GEMM: C[MxN] = A[MxK] * Bt[NxK]^T  (m97 structure) ----------------
// EPI 0: f32 MxN.  EPI 1: bf16 [B,H,S,dh] (SC: pre-scale by log2e).  EPI 2: bf16 [B,H,dh,S]
template<int EPI, int SC>
__global__ __launch_bounds__(256)
void gemm_bt_kernel(const bf16* __restrict__ A, const bf16* __restrict__ Bt,
                    void* __restrict__ Cout) {
  const int K = D_, N = D_;
  __shared__ bf16 As[128][32];
  __shared__ bf16 Bs[128][32];
  const int tid = threadIdx.x;
  const int brow = blockIdx.y * 128, bcol = blockIdx.x * 128;
  const int wave = tid >> 6, lane = tid & 63;
  const int wr = (wave >> 1) * 64, wc = (wave & 1) * 64;
  const int lrow = lane & 15, lgrp = lane >> 4;

  f32x4 acc[4][4] = {};

  const bf16* ag = A + (size_t)(brow + (tid >> 2)) * K + (tid & 3) * 8;
  const bf16* bg = Bt + (size_t)(bcol + (tid >> 2)) * K + (tid & 3) * 8;
  const size_t rstep = (size_t)64 * K;
  bf16* al = &As[0][0] + tid * 8;
  bf16* bl = &Bs[0][0] + tid * 8;

  for (int k0 = 0; k0 < K; k0 += 32) {
    __syncthreads();
    gld_lds16(ag + k0, al);
    gld_lds16(ag + k0 + rstep, al + 64 * 32);
    gld_lds16(bg + k0, bl);
    gld_lds16(bg + k0 + rstep, bl + 64 * 32);
    __syncthreads();
    bf16x8 af[4], bfr[4];
#pragma unroll
    for (int i = 0; i < 4; ++i) {
      af[i]  = *(const bf16x8*)&As[wr + i * 16 + lrow][lgrp * 8];
      bfr[i] = *(const bf16x8*)&Bs[wc + i * 16 + lrow][lgrp * 8];
    }
#pragma unroll
    for (int mi = 0; mi < 4; ++mi)
#pragma unroll
      for (int ni = 0; ni < 4; ++ni)
        acc[mi][ni] = mfma16(af[mi], bfr[ni], acc[mi][ni]);
  }

#pragma unroll
  for (int mi = 0; mi < 4; ++mi) {
    const int rowb = brow + wr + mi * 16 + lgrp * 4;
#pragma unroll
    for (int ni = 0; ni < 4; ++ni) {
      const int col = bcol + wc + ni * 16 + lrow;
#pragma unroll
      for (int r = 0; r < 4; ++r) {
        float v = acc[mi][ni][r];
        if (SC) v *= LOG2E;
        const int m = rowb + r;
        if (EPI == 0) {
          ((float*)Cout)[(size_t)m * N + col] = v;
        } else {
          const int bb = m >> 11, s = m & (S_ - 1);
          const int hh = col >> 6, d = col & (DH_ - 1);
          if (EPI == 1)
            ((bf16*)Cout)[((size_t)((bb * H_ + hh) * S_ + s)) * DH_ + d] = (bf16)v;
          else
            ((bf16*)Cout)[((size_t)((bb * H_ + hh) * DH_ + d)) * S_ + s] = (bf16)v;
        }
      }
    }
  }
}

// ---------------- flash attention v4: swapped QK^T, lane-local softmax ----------------
// 1024 blocks (XCD-swizzled), 512 thr = 8 waves; wave owns 16 q-rows; lane owns 1 q-row.
// K/V double-buffered LDS (XOR-swizzled), exp2-domain, defer-max.
__global__ __launch_bounds__(512, 6)
void attn_kernel(const bf16* __restrict__ Q, const bf16* __restrict__ Kb,
                 const bf16* __restrict__ Vt, const float* __restrict__ tab,
                 bf16* __restrict__ Oa) {
  __shared__ bf16 Ks[2][64 * 64];     // [s_local][d], rows 128B, XOR-swizzled
  __shared__ bf16 Vs[2][64 * 64];     // [d][s_local], rows 128B, XOR-swizzled
  __shared__ bf16 P_lds[8][16][72];   // per-wave P[q][k], rows padded to 144B
  __shared__ float bc[8][16];         // per-wave broadcast (scale / final l)

  const int bid = blockIdx.x;
  const int w = ((bid & 7) << 7) + (bid >> 3);   // XCD x owns 8 full (b,h) panels
  const int qt = w & 15, h = (w >> 4) & 15, b = w >> 8;
  const int tid = threadIdx.x;
  const int wave = tid >> 6, lane = tid & 63;
  const int lrow = lane & 15, lgrp = lane >> 4;
  const int q0 = qt * 128 + wave * 16;

  const bf16* Qp = Q + (size_t)(b * H_ + h) * S_ * DH_;
  const bf16* Kp = Kb + (size_t)(b * H_ + h) * S_ * DH_;
  const bf16* Vp = Vt + (size_t)(b * H_ + h) * DH_ * S_;
  // lane's q-row = q0+lrow; bias idx = (s - t) + 2047, s = s0+st*16+lgrp*4+r
  const float* btab = tab + h * 4096 + 2047 - q0 - lrow;

  // staging: thread tid stages row tid>>3, 16B chunk (tid&7), source pre-XOR-swizzled
  const int srow = tid >> 3;                                     // 0..63
  const int ce = ((((tid & 7) << 4) ^ ((srow & 7) << 4)) >> 1);  // swizzled col (elems)
  const bf16* ksrc = Kp + (size_t)srow * DH_ + ce;
  const bf16* vsrc = Vp + (size_t)srow * S_ + ce;
  bf16* kdst0 = &Ks[0][0] + tid * 8;
  bf16* vdst0 = &Vs[0][0] + tid * 8;
  const int swz = (lrow & 7) << 4;   // read-side byte XOR

  // Q fragment (B-operand): lane holds Q[q0+lrow][lgrp*8..+8] per kc
  bf16x8 qf[2];
#pragma unroll
  for (int kc = 0; kc < 2; ++kc)
    qf[kc] = *(const bf16x8*)&Qp[(size_t)(q0 + lrow) * DH_ + kc * 32 + lgrp * 8];

  float m_r = -3.0e38f, l_r = 0.f;
  f32x4 o[4] = {};

  // prologue: stage tile 0 into buf 0
  gld_lds16(ksrc, kdst0);
  gld_lds16(vsrc, vdst0);
  __syncthreads();

  for (int s0 = 0; s0 < S_; s0 += 64) {
    const int buf = (s0 >> 6) & 1;
    if (s0 + 64 < S_) {           // issue-early: next tile into other buffer
      const int nb = buf ^ 1;
      gld_lds16(ksrc + (size_t)(s0 + 64) * DH_, kdst0 + nb * 4096);
      gld_lds16(vsrc + (s0 + 64), vdst0 + nb * 4096);
    }
    const char* kb = (const char*)&Ks[buf][0];
    const char* vb = (const char*)&Vs[buf][0];

    // swapped QK^T: sc[st] = K_st * Q -> D[row=k-local][col=q-local]
    // lane: q = q0+lrow, k(st,r) = s0 + st*16 + lgrp*4 + r
    f32x4 sc[4] = {};
#pragma unroll
    for (int kc = 0; kc < 2; ++kc) {
      bf16x8 kf[4];
#pragma unroll
      for (int st = 0; st < 4; ++st)
        kf[st] = *(const bf16x8*)(kb + (st * 16 + lrow) * 128 +
                                  (((kc << 6) + (lgrp << 4)) ^ swz));
#pragma unroll
      for (int st = 0; st < 4; ++st)
        sc[st] = mfma16(kf[st], qf[kc], sc[st]);
    }

    // bias add (exp2-domain table), vec loads
#pragma unroll
    for (int st = 0; st < 4; ++st) {
      f32x4u bb = *(const f32x4u*)(btab + s0 + st * 16 + lgrp * 4);
#pragma unroll
      for (int r = 0; r < 4; ++r) sc[st][r] += bb[r];
    }
    // row max: in-lane tree (16 vals) + 2 shuffles across lgrp
    f32x4 mx01, mx;
#pragma unroll
    for (int r = 0; r < 4; ++r) mx01[r] = fmaxf(sc[0][r], sc[1][r]);
#pragma unroll
    for (int r = 0; r < 4; ++r) mx[r] = fmaxf(mx01[r], fmaxf(sc[2][r], sc[3][r]));
    float pmax = fmaxf(fmaxf(mx[0], mx[1]), fmaxf(mx[2], mx[3]));
    pmax = fmaxf(pmax, __shfl_xor(pmax, 16));
    pmax = fmaxf(pmax, __shfl_xor(pmax, 32));

    // defer-max: rescale only when some row grew by > 11.5 (= 8 nats)
    if (__any(pmax > m_r + 11.5f)) {
      const float mn = fmaxf(m_r, pmax);
      const float scale = exp2f(m_r - mn);
      m_r = mn;
      l_r *= scale;
      if (lgrp == 0) bc[wave][lrow] = scale;        // broadcast scale[q] to PV layout
      f32x4 s4 = *(const f32x4*)&bc[wave][lgrp * 4];
#pragma unroll
      for (int dt = 0; dt < 4; ++dt)
#pragma unroll
        for (int r = 0; r < 4; ++r) o[dt][r] *= s4[r];
    }

    // p = exp2(s - m), row sum (in-lane tree + 2 shuffles)
    f32x4 rs4 = {0.f, 0.f, 0.f, 0.f};
#pragma unroll
    for (int st = 0; st < 4; ++st) {
#pragma unroll
      for (int r = 0; r < 4; ++r) sc[st][r] = exp2f(sc[st][r] - m_r);
      rs4 += sc[st];
    }
    float rs = (rs4[0] + rs4[1]) + (rs4[2] + rs4[3]);
    rs += __shfl_xor(rs, 16);
    rs += __shfl_xor(rs, 32);
    l_r += rs;

    // P[q=lrow][k] -> LDS as packed b64 (4 bf16 = r0..3 of this (st,lgrp))
#pragma unroll
    for (int st = 0; st < 4; ++st) {
      bf16x4 pk = {(bf16)sc[st][0], (bf16)sc[st][1], (bf16)sc[st][2], (bf16)sc[st][3]};
      *(bf16x4*)&P_lds[wave][lrow][st * 16 + lgrp * 4] = pk;
    }

    // PV: A = P (contiguous b128), B = V rows from swizzled Vs
    bf16x8 pf[2];
#pragma unroll
    for (int kc = 0; kc < 2; ++kc)
      pf[kc] = *(const bf16x8*)&P_lds[wave][lrow][kc * 32 + lgrp * 8];
#pragma unroll
    for (int dt = 0; dt < 4; ++dt) {
      bf16x8 vf0 = *(const bf16x8*)(vb + (dt * 16 + lrow) * 128 + ((lgrp << 4) ^ swz));
      bf16x8 vf1 = *(const bf16x8*)(vb + (dt * 16 + lrow) * 128 + ((64 + (lgrp << 4)) ^ swz));
      o[dt] = mfma16(pf[0], vf0, o[dt]);
      o[dt] = mfma16(pf[1], vf1, o[dt]);
    }

    __syncthreads();   // publishes next buf (vmcnt) + all LDS reads done (lgkm)
  }

  // final: broadcast l[q] into PV output layout, normalize, store
  if (lgrp == 0) bc[wave][lrow] = l_r;
  f32x4 l4 = *(const f32x4*)&bc[wave][lgrp * 4];
  float inv[4];
#pragma unroll
  for (int r = 0; r < 4; ++r) inv[r] = 1.0f / l4[r];
#pragma unroll
  for (int dt = 0; dt < 4; ++dt)
#pragma unroll
    for (int r = 0; r < 4; ++r) {
      const int t = q0 + lgrp * 4 + r;
      const int d = dt * 16 + lrow;
      Oa[((size_t)(b * S_ + t)) * D_ + h * DH_ + d] = (bf16)(o[dt][r] * inv[r]);
    }
}

// ---------------- launch ----------------
extern "C" void kernel_launch(void* const* d_in, const int* in_sizes, int n_in,
                              void* d_out, int out_size, void* d_ws, size_t ws_size,
                              hipStream_t stream) {
  const float* Xq   = (const float*)d_in[0];
  const float* Xkv  = (const float*)d_in[1];
  const float* Wq   = (const float*)d_in[2];
  const float* Wk   = (const float*)d_in[3];
  const float* Wv   = (const float*)d_in[4];
  const float* Wo   = (const float*)d_in[5];
  const float* relb = (const float*)d_in[6];
  float* out = (float*)d_out;

  char* ws = (char*)d_ws;
  const size_t SZ_X = (size_t)M_ * D_ * 2;   // 16 MB
  const size_t SZ_W = (size_t)D_ * D_ * 2;   // 2 MB
  bf16* Xq_b  = (bf16*)(ws);
  bf16* Xkv_b = (bf16*)(ws + SZ_X);
  bf16* Wq_t  = (bf16*)(ws + 2 * SZ_X);
  bf16* Wk_t  = (bf16*)(ws + 2 * SZ_X + SZ_W);
  bf16* Wv_t  = (bf16*)(ws + 2 * SZ_X + 2 * SZ_W);
  bf16* Wo_t  = (bf16*)(ws + 2 * SZ_X + 3 * SZ_W);
  bf16* Qb    = (bf16*)(ws + 2 * SZ_X + 4 * SZ_W);
  bf16* Kbuf  = (bf16*)(ws + 3 * SZ_X + 4 * SZ_W);
  bf16* Vt    = (bf16*)(ws + 4 * SZ_X + 4 * SZ_W);
  bf16* Ab    = (bf16*)(ws + 5 * SZ_X + 4 * SZ_W);
  float* tab  = (float*)(ws + 6 * SZ_X + 4 * SZ_W);  // 16*4096 f32

  cast_kernel<<<8192, 256, 0, stream>>>(Xq, Xq_b);
  cast_kernel<<<8192, 256, 0, stream>>>(Xkv, Xkv_b);
  transpose_cast_kernel<<<dim3(32, 32), dim3(32, 8), 0, stream>>>(Wq, Wq_t);
  transpose_cast_kernel<<<dim3(32, 32), dim3(32, 8), 0, stream>>>(Wk, Wk_t);
  transpose_cast_kernel<<<dim3(32, 32), dim3(32, 8), 0, stream>>>(Wv, Wv_t);
  transpose_cast_kernel<<<dim3(32, 32), dim3(32, 8), 0, stream>>>(Wo, Wo_t);
  bias_table_kernel<<<256, 256, 0, stream>>>(relb, tab);

  dim3 ggrid(D_ / 128, M_ / 128);   // (8, 64)
  gemm_bt_kernel<1, 1><<<ggrid, 256, 0, stream>>>(Xq_b, Wq_t, Qb);   // Q pre-scaled by log2e
  gemm_bt_kernel<1, 0><<<ggrid, 256, 0, stream>>>(Xkv_b, Wk_t, Kbuf);
  gemm_bt_kernel<2, 0><<<ggrid, 256, 0, stream>>>(Xkv_b, Wv_t, Vt);
  attn_kernel<<<1024, 512, 0, stream>>>(Qb, Kbuf, Vt, tab, Ab);
  gemm_bt_kernel<0, 0><<<ggrid, 256, 0, stream>>>(Ab, Wo_t, out);
}

// Round 6
// 259.903 us; speedup vs baseline: 1.7905x; 1.2231x over previous
//
#include <hip/hip_runtime.h>
#include <hip/hip_bf16.h>
#include <math.h>

typedef __bf16 bf16;
typedef __attribute__((ext_vector_type(8))) __bf16 bf16x8;
typedef __attribute__((ext_vector_type(4))) __bf16 bf16x4;
typedef __attribute__((ext_vector_type(4))) float f32x4;
typedef __attribute__((ext_vector_type(4), aligned(4))) float f32x4u;  // unaligned vec load

#define B_  4
#define S_  2048
#define D_  1024
#define H_  16
#define DH_ 64
#define M_  (B_ * S_)   // 8192
#define LOG2E 1.44269504088896f

static __device__ __forceinline__ f32x4 mfma16(bf16x8 a, bf16x8 b, f32x4 c) {
  return __builtin_amdgcn_mfma_f32_16x16x32_bf16(a, b, c, 0, 0, 0);
}

static __device__ __forceinline__ void gld_lds16(const bf16* g, bf16* l) {
  __builtin_amdgcn_global_load_lds(
      (const __attribute__((address_space(1))) void*)g,
      (__attribute__((address_space(3))) void*)l, 16, 0, 0);
}

// ---------------- f32 -> bf16 cast, both inputs in one dispatch ----------------
__global__ __launch_bounds__(256)
void cast2_kernel(const float* __restrict__ a, const float* __restrict__ bsrc,
                  bf16* __restrict__ oa, bf16* __restrict__ ob) {
  const int blk = blockIdx.x;
  const float* in = (blk < 8192) ? a : bsrc;
  bf16* out = (blk < 8192) ? oa : ob;
  size_t i = ((size_t)(blk & 8191) * 256 + threadIdx.x) * 4;
  float4 v = *(const float4*)(in + i);
  bf16x4 o = {(bf16)v.x, (bf16)v.y, (bf16)v.z, (bf16)v.w};
  *(bf16x4*)(out + i) = o;
}

// ---------------- transpose+cast all 4 weights: out[n][k] = bf16(in[k][n]) ----------------
__global__ __launch_bounds__(256)
void transpose_cast4_kernel(const float* __restrict__ w0, const float* __restrict__ w1,
                            const float* __restrict__ w2, const float* __restrict__ w3,
                            bf16* __restrict__ o0, bf16* __restrict__ o1,
                            bf16* __restrict__ o2, bf16* __restrict__ o3) {
  __shared__ float tile[32][33];
  const int z = blockIdx.z;
  const float* in = (z == 0) ? w0 : (z == 1) ? w1 : (z == 2) ? w2 : w3;
  bf16* out = (z == 0) ? o0 : (z == 1) ? o1 : (z == 2) ? o2 : o3;
  int n0 = blockIdx.x * 32, k0 = blockIdx.y * 32;
  int tx = threadIdx.x, ty = threadIdx.y;
#pragma unroll
  for (int j = 0; j < 32; j += 8)
    tile[ty + j][tx] = in[(size_t)(k0 + ty + j) * D_ + n0 + tx];
  __syncthreads();
#pragma unroll
  for (int j = 0; j < 32; j += 8)
    out[(size_t)(n0 + ty + j) * D_ + k0 + tx] = (bf16)tile[tx][ty + j];
}

// ---------------- bias table (exp2 domain, fixed-max fold): tab = bias*log2e - 64 ----------------
__global__ __launch_bounds__(256)
void bias_table_kernel(const float* __restrict__ rel_bias, float* __restrict__ tab) {
  int i = blockIdx.x * 256 + threadIdx.x;   // 16*4096 entries
  int h = i >> 12, dp = i & 4095;
  int rel = dp - 2047;                       // rel = s - t
  int bucket = (rel > 0) ? 16 : 0;
  int rp = rel < 0 ? -rel : rel;
  if (rp < 8) {
    bucket += rp;
  } else {
    // ln(rp/8)/ln(16)*8 == 2*log2(rp/8); exact at rp = 16,32,64,128 boundaries
    int large = 8 + (int)(2.0f * __log2f((float)rp * 0.125f));
    bucket += (large < 15 ? large : 15);
  }
  tab[i] = rel_bias[bucket * H_ + h] * LOG2E - 64.0f;   // fixed max M=64 folded in
}

// ---------------- fused Q/K/V projection GEMMs (z = 0,1,2) ----------------
// z0: Qb = Xq*Wq^T scaled by log2e -> [B,H,S,dh]; z1: Kbuf -> [B,H,S,dh]; z2: Vt -> [B,H,dh,S]
__global__ __launch_bounds__(256)
void proj_gemm_kernel(const bf16* __restrict__ Xq, const bf16* __restrict__ Xkv,
                      const bf16* __restrict__ Wq, const bf16* __restrict__ Wk,
                      const bf16* __restrict__ Wv,
                      bf16* __restrict__ Qb, bf16* __restrict__ Kb, bf16* __restrict__ Vt) {
  const int K = D_;
  __shared__ bf16 As[128][32];
  __shared__ bf16 Bs[128][32];
  const int z = blockIdx.z;
  const bf16* A  = (z == 0) ? Xq : Xkv;
  const bf16* Bt = (z == 0) ? Wq : (z == 1) ? Wk : Wv;
  const int tid = threadIdx.x;
  const int brow = blockIdx.y * 128, bcol = blockIdx.x * 128;
  const int wave = tid >> 6, lane = tid & 63;
  const int wr = (wave >> 1) * 64, wc = (wave & 1) * 64;
  const int lrow = lane & 15, lgrp = lane >> 4;

  f32x4 acc[4][4] = {};

  const bf16* ag = A + (size_t)(brow + (tid >> 2)) * K + (tid & 3) * 8;
  const bf16* bg = Bt + (size_t)(bcol + (tid >> 2)) * K + (tid & 3) * 8;
  const size_t rstep = (size_t)64 * K;
  bf16* al = &As[0][0] + tid * 8;
  bf16* bl = &Bs[0][0] + tid * 8;

  for (int k0 = 0; k0 < K; k0 += 32) {
    __syncthreads();
    gld_lds16(ag + k0, al);
    gld_lds16(ag + k0 + rstep, al + 64 * 32);
    gld_lds16(bg + k0, bl);
    gld_lds16(bg + k0 + rstep, bl + 64 * 32);
    __syncthreads();
    bf16x8 af[4], bfr[4];
#pragma unroll
    for (int i = 0; i < 4; ++i) {
      af[i]  = *(const bf16x8*)&As[wr + i * 16 + lrow][lgrp * 8];
      bfr[i] = *(const bf16x8*)&Bs[wc + i * 16 + lrow][lgrp * 8];
    }
#pragma unroll
    for (int mi = 0; mi < 4; ++mi)
#pragma unroll
      for (int ni = 0; ni < 4; ++ni)
        acc[mi][ni] = mfma16(af[mi], bfr[ni], acc[mi][ni]);
  }

  const float scl = (z == 0) ? LOG2E : 1.0f;
#pragma unroll
  for (int mi = 0; mi < 4; ++mi) {
    const int rowb = brow + wr + mi * 16 + lgrp * 4;
#pragma unroll
    for (int ni = 0; ni < 4; ++ni) {
      const int col = bcol + wc + ni * 16 + lrow;
#pragma unroll
      for (int r = 0; r < 4; ++r) {
        const float v = acc[mi][ni][r] * scl;
        const int m = rowb + r;
        const int bb = m >> 11, s = m & (S_ - 1);
        const int hh = col >> 6, d = col & (DH_ - 1);
        if (z == 0)
          Qb[((size_t)((bb * H_ + hh) * S_ + s)) * DH_ + d] = (bf16)v;
        else if (z == 1)
          Kb[((size_t)((bb * H_ + hh) * S_ + s)) * DH_ + d] = (bf16)v;
        else
          Vt[((size_t)((bb * H_ + hh) * DH_ + d)) * S_ + s] = (bf16)v;
      }
    }
  }
}

// ---------------- output GEMM: out[MxN] f32 = Ab * Wo_t^T ----------------
__global__ __launch_bounds__(256)
void gemm_out_kernel(const bf16* __restrict__ A, const bf16* __restrict__ Bt,
                     float* __restrict__ Cout) {
  const int K = D_, N = D_;
  __shared__ bf16 As[128][32];
  __shared__ bf16 Bs[128][32];
  const int tid = threadIdx.x;
  const int brow = blockIdx.y * 128, bcol = blockIdx.x * 128;
  const int wave = tid >> 6, lane = tid & 63;
  const int wr = (wave >> 1) * 64, wc = (wave & 1) * 64;
  const int lrow = lane & 15, lgrp = lane >> 4;

  f32x4 acc[4][4] = {};

  const bf16* ag = A + (size_t)(brow + (tid >> 2)) * K + (tid & 3) * 8;
  const bf16* bg = Bt + (size_t)(bcol + (tid >> 2)) * K + (tid & 3) * 8;
  const size_t rstep = (size_t)64 * K;
  bf16* al = &As[0][0] + tid * 8;
  bf16* bl = &Bs[0][0] + tid * 8;

  for (int k0 = 0; k0 < K; k0 += 32) {
    __syncthreads();
    gld_lds16(ag + k0, al);
    gld_lds16(ag + k0 + rstep, al + 64 * 32);
    gld_lds16(bg + k0, bl);
    gld_lds16(bg + k0 + rstep, bl + 64 * 32);
    __syncthreads();
    bf16x8 af[4], bfr[4];
#pragma unroll
    for (int i = 0; i < 4; ++i) {
      af[i]  = *(const bf16x8*)&As[wr + i * 16 + lrow][lgrp * 8];
      bfr[i] = *(const bf16x8*)&Bs[wc + i * 16 + lrow][lgrp * 8];
    }
#pragma unroll
    for (int mi = 0; mi < 4; ++mi)
#pragma unroll
      for (int ni = 0; ni < 4; ++ni)
        acc[mi][ni] = mfma16(af[mi], bfr[ni], acc[mi][ni]);
  }

#pragma unroll
  for (int mi = 0; mi < 4; ++mi) {
    const int rowb = brow + wr + mi * 16 + lgrp * 4;
#pragma unroll
    for (int ni = 0; ni < 4; ++ni) {
      const int col = bcol + wc + ni * 16 + lrow;
#pragma unroll
      for (int r = 0; r < 4; ++r)
        Cout[(size_t)(rowb + r) * N + col] = acc[mi][ni][r];
    }
  }
}

// ---------------- flash attention v5: fixed-max, swapped QK^T, QBLK=256 ----------------
// 512 blocks (XCD-swizzled, all-resident), 512 thr = 8 waves; wave owns 32 q-rows.
// K/V double-buffered LDS (XOR-swizzled); P in K-style swizzled LDS; no online max.
__global__ __launch_bounds__(512, 4)
void attn_kernel(const bf16* __restrict__ Q, const bf16* __restrict__ Kb,
                 const bf16* __restrict__ Vt, const float* __restrict__ tab,
                 bf16* __restrict__ Oa) {
  __shared__ bf16 Ks[2][64 * 64];    // [s_local][d], rows 128B, XOR-swizzled
  __shared__ bf16 Vs[2][64 * 64];    // [d][s_local], rows 128B, XOR-swizzled
  __shared__ bf16 P_lds[8][2048];    // per-wave P[32][64], rows 128B, XOR-swizzled
  __shared__ float bc[8][2][16];     // per-wave final-l broadcast

  const int bid = blockIdx.x;
  const int w = ((bid & 7) << 6) + (bid >> 3);   // XCD x owns 8 full (b,h) panels
  const int qt = w & 7, h = (w >> 3) & 15, b = w >> 7;
  const int tid = threadIdx.x;
  const int wave = tid >> 6, lane = tid & 63;
  const int lrow = lane & 15, lgrp = lane >> 4;
  const int q0 = qt * 256 + wave * 32;

  const bf16* Qp = Q + (size_t)(b * H_ + h) * S_ * DH_;
  const bf16* Kp = Kb + (size_t)(b * H_ + h) * S_ * DH_;
  const bf16* Vp = Vt + (size_t)(b * H_ + h) * DH_ * S_;
  // bias idx = (s - t) + 2047; s = s0+st*16+lgrp*4+r, t = q0+mi*16+lrow
  const float* btab = tab + h * 4096 + 2047 - q0 - lrow;

  // staging: thread tid stages row tid>>3, 16B chunk (tid&7), source pre-XOR-swizzled
  const int srow = tid >> 3;                                     // 0..63
  const int ce = ((((tid & 7) << 4) ^ ((srow & 7) << 4)) >> 1);  // swizzled col (elems)
  const bf16* ksrc = Kp + (size_t)srow * DH_ + ce;
  const bf16* vsrc = Vp + (size_t)srow * S_ + ce;
  bf16* kdst0 = &Ks[0][0] + tid * 8;
  bf16* vdst0 = &Vs[0][0] + tid * 8;
  const int swz = (lrow & 7) << 4;   // read-side byte XOR (row&7 == lrow&7 for all rows used)
  bf16* Pw = P_lds[wave];

  // Q fragments (B-operand): lane holds Q[q0+mi*16+lrow][...]
  bf16x8 qf[2][2];
#pragma unroll
  for (int mi = 0; mi < 2; ++mi)
#pragma unroll
    for (int kc = 0; kc < 2; ++kc)
      qf[mi][kc] = *(const bf16x8*)&Qp[(size_t)(q0 + mi * 16 + lrow) * DH_ + kc * 32 + lgrp * 8];

  float l_r[2] = {0.f, 0.f};
  f32x4 o[2][4] = {};

  // prologue: stage tile 0 into buf 0
  gld_lds16(ksrc, kdst0);
  gld_lds16(vsrc, vdst0);
  __syncthreads();

  for (int s0 = 0; s0 < S_; s0 += 64) {
    const int buf = (s0 >> 6) & 1;
    if (s0 + 64 < S_) {           // issue-early: next tile into other buffer
      const int nb = buf ^ 1;
      gld_lds16(ksrc + (size_t)(s0 + 64) * DH_, kdst0 + nb * 4096);
      gld_lds16(vsrc + (s0 + 64), vdst0 + nb * 4096);
    }
    const char* kbp = (const char*)&Ks[buf][0];
    const char* vbp = (const char*)&Vs[buf][0];

#pragma unroll
    for (int mi = 0; mi < 2; ++mi) {
      // acc initialized with bias (C-in of first MFMA); exp2-domain, fixed max folded in
      f32x4 sc[4];
#pragma unroll
      for (int st = 0; st < 4; ++st)
        sc[st] = *(const f32x4u*)(btab + s0 + st * 16 + lgrp * 4 - mi * 16);
      // swapped QK^T: D[row=k-local][col=q-local]; lane q = q0+mi*16+lrow
#pragma unroll
      for (int kc = 0; kc < 2; ++kc) {
        bf16x8 kf[4];
#pragma unroll
        for (int st = 0; st < 4; ++st)
          kf[st] = *(const bf16x8*)(kbp + (st * 16 + lrow) * 128 +
                                    (((kc << 6) + (lgrp << 4)) ^ swz));
#pragma unroll
        for (int st = 0; st < 4; ++st)
          sc[st] = mfma16(kf[st], qf[mi][kc], sc[st]);
      }
      // p = exp2(s); row sum (in-lane tree + 2 shuffles)
      f32x4 rs4 = {0.f, 0.f, 0.f, 0.f};
#pragma unroll
      for (int st = 0; st < 4; ++st) {
#pragma unroll
        for (int r = 0; r < 4; ++r) sc[st][r] = exp2f(sc[st][r]);
        rs4 += sc[st];
      }
      float rs = (rs4[0] + rs4[1]) + (rs4[2] + rs4[3]);
      rs += __shfl_xor(rs, 16);
      rs += __shfl_xor(rs, 32);
      l_r[mi] += rs;
      // P[q-local=mi*16+lrow][k] -> swizzled LDS (b64 packed)
#pragma unroll
      for (int st = 0; st < 4; ++st) {
        bf16x4 pk = {(bf16)sc[st][0], (bf16)sc[st][1], (bf16)sc[st][2], (bf16)sc[st][3]};
        *(bf16x4*)((char*)Pw + (mi * 16 + lrow) * 128 + (((st << 5) + (lgrp << 3)) ^ swz)) = pk;
      }
    }

    // PV: A = P (swizzled b128 reads), B = V rows from swizzled Vs
    bf16x8 pf[2][2];
#pragma unroll
    for (int mi = 0; mi < 2; ++mi)
#pragma unroll
      for (int kc = 0; kc < 2; ++kc)
        pf[mi][kc] = *(const bf16x8*)((char*)Pw + (mi * 16 + lrow) * 128 +
                                      (((kc << 6) + (lgrp << 4)) ^ swz));
#pragma unroll
    for (int dt = 0; dt < 4; ++dt) {
      bf16x8 vf0 = *(const bf16x8*)(vbp + (dt * 16 + lrow) * 128 + ((lgrp << 4) ^ swz));
      bf16x8 vf1 = *(const bf16x8*)(vbp + (dt * 16 + lrow) * 128 + ((64 + (lgrp << 4)) ^ swz));
#pragma unroll
      for (int mi = 0; mi < 2; ++mi) {
        o[mi][dt] = mfma16(pf[mi][0], vf0, o[mi][dt]);
        o[mi][dt] = mfma16(pf[mi][1], vf1, o[mi][dt]);
      }
    }

    __syncthreads();   // publishes next buf (vmcnt) + all LDS reads done (lgkm)
  }

  // final: broadcast l[q] into PV output layout, normalize, store
#pragma unroll
  for (int mi = 0; mi < 2; ++mi)
    if (lgrp == 0) bc[wave][mi][lrow] = l_r[mi];
#pragma unroll
  for (int mi = 0; mi < 2; ++mi) {
    f32x4 l4 = *(const f32x4*)&bc[wave][mi][lgrp * 4];
    float inv[4];
#pragma unroll
    for (int r = 0; r < 4; ++r) inv[r] = 1.0f / l4[r];
#pragma unroll
    for (int dt = 0; dt < 4; ++dt)
#pragma unroll
      for (int r = 0; r < 4; ++r) {
        const int t = q0 + mi * 16 + lgrp * 4 + r;
        const int d = dt * 16 + lrow;
        Oa[((size_t)(b * S_ + t)) * D_ + h * DH_ + d] = (bf16)(o[mi][dt][r] * inv[r]);
      }
  }
}

// ---------------- launch ----------------
extern "C" void kernel_launch(void* const* d_in, const int* in_sizes, int n_in,
                              void* d_out, int out_size, void* d_ws, size_t ws_size,
                              hipStream_t stream) {
  const float* Xq   = (const float*)d_in[0];
  const float* Xkv  = (const float*)d_in[1];
  const float* Wq   = (const float*)d_in[2];
  const float* Wk   = (const float*)d_in[3];
  const float* Wv   = (const float*)d_in[4];
  const float* Wo   = (const float*)d_in[5];
  const float* relb = (const float*)d_in[6];
  float* out = (float*)d_out;

  char* ws = (char*)d_ws;
  const size_t SZ_X = (size_t)M_ * D_ * 2;   // 16 MB
  const size_t SZ_W = (size_t)D_ * D_ * 2;   // 2 MB
  bf16* Xq_b  = (bf16*)(ws);
  bf16* Xkv_b = (bf16*)(ws + SZ_X);
  bf16* Wq_t  = (bf16*)(ws + 2 * SZ_X);
  bf16* Wk_t  = (bf16*)(ws + 2 * SZ_X + SZ_W);
  bf16* Wv_t  = (bf16*)(ws + 2 * SZ_X + 2 * SZ_W);
  bf16* Wo_t  = (bf16*)(ws + 2 * SZ_X + 3 * SZ_W);
  bf16* Qb    = (bf16*)(ws + 2 * SZ_X + 4 * SZ_W);
  bf16* Kbuf  = (bf16*)(ws + 3 * SZ_X + 4 * SZ_W);
  bf16* Vt    = (bf16*)(ws + 4 * SZ_X + 4 * SZ_W);
  bf16* Ab    = (bf16*)(ws + 5 * SZ_X + 4 * SZ_W);
  float* tab  = (float*)(ws + 6 * SZ_X + 4 * SZ_W);  // 16*4096 f32

  cast2_kernel<<<16384, 256, 0, stream>>>(Xq, Xkv, Xq_b, Xkv_b);
  transpose_cast4_kernel<<<dim3(32, 32, 4), dim3(32, 8), 0, stream>>>(
      Wq, Wk, Wv, Wo, Wq_t, Wk_t, Wv_t, Wo_t);
  bias_table_kernel<<<256, 256, 0, stream>>>(relb, tab);

  proj_gemm_kernel<<<dim3(8, 64, 3), 256, 0, stream>>>(
      Xq_b, Xkv_b, Wq_t, Wk_t, Wv_t, Qb, Kbuf, Vt);
  attn_kernel<<<512, 512, 0, stream>>>(Qb, Kbuf, Vt, tab, Ab);
  gemm_out_kernel<<<dim3(8, 64), 256, 0, stream>>>(Ab, Wo_t, out);
}